// Round 15
// baseline (217.912 us; speedup 1.0000x reference)
//
#include <hip/hip_runtime.h>

typedef __bf16 bf16;
typedef __bf16 bf16x8 __attribute__((ext_vector_type(8)));
typedef __bf16 bf16x4 __attribute__((ext_vector_type(4)));
typedef float f32x4 __attribute__((ext_vector_type(4)));

#define LCTX 512
#define HD 1024

__device__ __forceinline__ float wave_sum(float v) {
    for (int off = 32; off; off >>= 1) v += __shfl_xor(v, off, 64);
    return v;
}
__device__ __forceinline__ float wave_max(float v) {
    for (int off = 32; off; off >>= 1) v = fmaxf(v, __shfl_xor(v, off, 64));
    return v;
}

// ---------------- prep: 4 weight transposes + lqconv + kpart ----------------
// blocks [0,5120): transpose (widened); [5120,6144): lqconv; [6144,6400): kpart
__global__ __launch_bounds__(256) void prep_kernel(const float* __restrict__ W3,
                                                   const float* __restrict__ Wc,
                                                   const float* __restrict__ Wf1,
                                                   const float* __restrict__ Wf2,
                                                   const float* __restrict__ lq,
                                                   const float* __restrict__ x,
                                                   const float* __restrict__ W1,
                                                   bf16* __restrict__ W3t, bf16* __restrict__ Wct,
                                                   bf16* __restrict__ Wf1t, bf16* __restrict__ Wf2t,
                                                   bf16* __restrict__ X,
                                                   float* __restrict__ kpartial) {
    __shared__ __align__(16) char smem[33792];
    int blk = blockIdx.x, t = threadIdx.x;
    if (blk < 5120) {
        float (*tile)[33] = (float(*)[33])smem;
        const float* W; bf16* Wt; int K, N, i;
        if (blk < 1024)      { W = W3;  Wt = W3t;  K = 1024; N = 1024; i = blk; }
        else if (blk < 2048) { W = Wc;  Wt = Wct;  K = 1024; N = 1024; i = blk - 1024; }
        else if (blk < 3072) { W = Wf2; Wt = Wf2t; K = 1024; N = 1024; i = blk - 2048; }
        else                 { W = Wf1; Wt = Wf1t; K = 2048; N = 1024; i = blk - 3072; }
        int k0 = (i >> 5) * 32, n0 = (i & 31) * 32;
        // read: thread t -> row kr = t>>3 (0..31), float4 at cols (t&7)*4
        int kr = t >> 3, cf = (t & 7) * 4;
        float4 rv = *(const float4*)(W + (size_t)(k0 + kr) * N + n0 + cf);
        *(float4*)&tile[kr][cf] = rv;
        __syncthreads();
        // write: thread t -> out row nr = t>>3, bf16x4 at ks (t&7)*4
        int nr = t >> 3, ck = (t & 7) * 4;
        bf16x4 o = {(bf16)tile[ck + 0][nr], (bf16)tile[ck + 1][nr],
                    (bf16)tile[ck + 2][nr], (bf16)tile[ck + 3][nr]};
        *(bf16x4*)(Wt + (size_t)(n0 + nr) * K + k0 + ck) = o;
    } else if (blk < 6144) {
        int i = (blk - 5120) * 256 + t;    // over 262144 float4s
        float4 v = ((const float4*)lq)[i];
        int row = i >> 8, h4 = i & 255;
        bf16x4 o = {(bf16)v.x, (bf16)v.y, (bf16)v.z, (bf16)v.w};
        *(bf16x4*)(X + (size_t)row * 2048 + 1024 + h4 * 4) = o;
    } else {
        // kpart: K-split f32 GEMM  M=64(batch) N=1024 K=1024, token-0 rows
        float (*xs)[68] = (float(*)[68])smem;
        float (*wsm)[64] = (float(*)[64])(smem + 17408);
        int kv = blk - 6144;                    // 0..255
        int n0 = (kv & 15) * 64, k0 = (kv >> 4) * 64;
#pragma unroll
        for (int i = 0; i < 4; i++) {
            int f = t + i * 256;
            int b = f >> 4, c = f & 15;
            *(float4*)&xs[b][c * 4] =
                *(const float4*)(x + (size_t)b * LCTX * HD + k0 + c * 4);
        }
#pragma unroll
        for (int i = 0; i < 4; i++) {
            int f = t + i * 256;
            int r = f >> 4, c = f & 15;
            *(float4*)&wsm[r][c * 4] =
                *(const float4*)(W1 + (size_t)(k0 + r) * 1024 + n0 + c * 4);
        }
        __syncthreads();
        int tb = t >> 4, tc = t & 15;
        int b0 = tb * 4;
        float acc[4][4] = {};
        for (int kk = 0; kk < 64; kk += 4) {
            float4 w0 = *(const float4*)&wsm[kk + 0][tc * 4];
            float4 w1 = *(const float4*)&wsm[kk + 1][tc * 4];
            float4 w2 = *(const float4*)&wsm[kk + 2][tc * 4];
            float4 w3 = *(const float4*)&wsm[kk + 3][tc * 4];
            float4 xv[4];
#pragma unroll
            for (int bi = 0; bi < 4; bi++) xv[bi] = *(const float4*)&xs[b0 + bi][kk];
#pragma unroll
            for (int bi = 0; bi < 4; bi++) {
                acc[bi][0] += xv[bi].x * w0.x + xv[bi].y * w1.x + xv[bi].z * w2.x + xv[bi].w * w3.x;
                acc[bi][1] += xv[bi].x * w0.y + xv[bi].y * w1.y + xv[bi].z * w2.y + xv[bi].w * w3.y;
                acc[bi][2] += xv[bi].x * w0.z + xv[bi].y * w1.z + xv[bi].z * w2.z + xv[bi].w * w3.z;
                acc[bi][3] += xv[bi].x * w0.w + xv[bi].y * w1.w + xv[bi].z * w2.w + xv[bi].w * w3.w;
            }
        }
        float* pout = kpartial + ((size_t)(kv >> 4) * 64 + b0) * 1024 + n0 + tc * 4;
#pragma unroll
        for (int bi = 0; bi < 4; bi++)
            *(float4*)(pout + (size_t)bi * 1024) =
                make_float4(acc[bi][0], acc[bi][1], acc[bi][2], acc[bi][3]);
    }
}

// ---------------- mmat (+inline kreduce): m[b,i] = W2[i,:] . k[b,:] ---------
__global__ __launch_bounds__(256) void mmat_kernel(const float* __restrict__ partial,
                                                   const float* __restrict__ b1,
                                                   const float* __restrict__ W2,
                                                   float* __restrict__ mout) {
    __shared__ float ks[1024];
    int b = blockIdx.x, i0 = blockIdx.y * 64, t = threadIdx.x;
    {
        float4 acc = ((const float4*)b1)[t];
#pragma unroll
        for (int kt = 0; kt < 16; kt++) {
            float4 v = ((const float4*)(partial + ((size_t)kt * 64 + b) * 1024))[t];
            acc.x += v.x; acc.y += v.y; acc.z += v.z; acc.w += v.w;
        }
        *(float4*)&ks[t * 4] = acc;
    }
    __syncthreads();
    int wave = t >> 6, lane = t & 63;
    for (int rr = 0; rr < 16; rr++) {
        int i = i0 + wave * 16 + rr;
        const float* wrow = W2 + (size_t)i * 1024;
        float s = 0.f;
#pragma unroll
        for (int j = 0; j < 4; j++) {
            float4 wv = ((const float4*)wrow)[lane + j * 64];
            const float4 kv = *(const float4*)&ks[(lane + j * 64) * 4];
            s += wv.x * kv.x + wv.y * kv.y + wv.z * kv.z + wv.w * kv.w;
        }
        s = wave_sum(s);
        if (lane == 0) mout[(size_t)b * 1024 + i] = s;
    }
}

// ---------------- att[b,l] = x[b,l,:] . m[b,:]  grid (64,32) ----------------
__global__ __launch_bounds__(256) void att_kernel(const float* __restrict__ x,
                                                  const float* __restrict__ m,
                                                  float* __restrict__ att) {
    __shared__ float ms[1024];
    int b = blockIdx.x, l0 = blockIdx.y * 16, t = threadIdx.x;
    *(float4*)&ms[t * 4] = ((const float4*)(m + (size_t)b * 1024))[t];
    __syncthreads();
    int wave = t >> 6, lane = t & 63;
    for (int rr = 0; rr < 4; rr++) {
        int l = l0 + wave * 4 + rr;
        const float* xr = x + ((size_t)b * LCTX + l) * HD;
        float s = 0.f;
#pragma unroll
        for (int j = 0; j < 4; j++) {
            float4 xv = ((const float4*)xr)[lane + j * 64];
            const float4 mv = *(const float4*)&ms[(lane + j * 64) * 4];
            s += xv.x * mv.x + xv.y * mv.y + xv.z * mv.z + xv.w * mv.w;
        }
        s = wave_sum(s);
        if (lane == 0) att[(size_t)b * LCTX + l] = s;
    }
}

// ---------------- ypart: softmax + partial y; ps stored TRANSPOSED ----------
// grid (64, 8): 512 blocks, 2/CU. ps_T[64][16] -> 4x ds_read_b128 per l-iter.
__global__ __launch_bounds__(256) void ypart_kernel(const float* __restrict__ att,
                                                    const unsigned char* __restrict__ mask,
                                                    const float* __restrict__ x,
                                                    float* __restrict__ ypartial) {
    __shared__ float psT[64][16];      // [l_local][pp]
    __shared__ float att_s[512];
    __shared__ int sstr;
    int b = blockIdx.x, lqi = blockIdx.y, t = threadIdx.x;
    int l0 = lqi * 64;
    int wave = t >> 6, lane = t & 63;
    if (t == 0) sstr = 4;
    if (t < 128) ((float4*)att_s)[t] = ((const float4*)(att + (size_t)b * LCTX))[t];
    __syncthreads();
    if (t < 128 && ((const unsigned int*)mask)[t] > 1u) sstr = 1;
    __syncthreads();
    int stride = sstr;
#pragma unroll
    for (int q = 0; q < 4; q++) {
        int pp = wave * 4 + q;
        size_t mbase = ((size_t)(b * 16 + pp)) * LCTX;
        float av[8];
#pragma unroll
        for (int j = 0; j < 8; j++) {
            int l = lane + j * 64;
            bool mk = mask[(mbase + l) * (size_t)stride] != 0;
            av[j] = mk ? -1e30f : att_s[l];
        }
        float mx = av[0];
#pragma unroll
        for (int j = 1; j < 8; j++) mx = fmaxf(mx, av[j]);
        mx = wave_max(mx);
        float s = 0.f;
#pragma unroll
        for (int j = 0; j < 8; j++) {
            av[j] = (av[j] <= -1e29f) ? 0.f : expf(av[j] - mx);
            s += av[j];
        }
        s = wave_sum(s);
        float sel = av[0];
#pragma unroll
        for (int j = 1; j < 8; j++) if (lqi == j) sel = av[j];
        psT[lane][pp] = sel * (1.f / s);
    }
    __syncthreads();
    float4 acc[16];
#pragma unroll
    for (int q = 0; q < 16; q++) acc[q] = make_float4(0.f, 0.f, 0.f, 0.f);
    const float4* xb = (const float4*)(x + ((size_t)b * LCTX + l0) * HD) + t;
    float4 xv = xb[0];
    for (int l = 0; l < 64; l++) {
        float4 cur = xv;
        if (l < 63) xv = xb[(size_t)(l + 1) * 256];   // prefetch next row
        f32x4 pv0 = *(const f32x4*)&psT[l][0];
        f32x4 pv1 = *(const f32x4*)&psT[l][4];
        f32x4 pv2 = *(const f32x4*)&psT[l][8];
        f32x4 pv3 = *(const f32x4*)&psT[l][12];
#pragma unroll
        for (int g = 0; g < 4; g++) {
            f32x4 pv = g == 0 ? pv0 : (g == 1 ? pv1 : (g == 2 ? pv2 : pv3));
#pragma unroll
            for (int j = 0; j < 4; j++) {
                float p = pv[j];
                int q = g * 4 + j;
                acc[q].x += p * cur.x; acc[q].y += p * cur.y;
                acc[q].z += p * cur.z; acc[q].w += p * cur.w;
            }
        }
    }
    float* yp = ypartial + ((size_t)lqi * 1024 + b * 16) * 1024 + t * 4;
#pragma unroll
    for (int q = 0; q < 16; q++)
        *(float4*)(yp + (size_t)q * 1024) = acc[q];
}

// ---------------- yred: y = bf16( sum of 8 partials ) -----------------------
__global__ __launch_bounds__(256) void yred_kernel(const float* __restrict__ ypartial,
                                                   bf16* __restrict__ y) {
    int i = blockIdx.x * 256 + threadIdx.x;   // over 262144 float4s of y
    float4 s = ((const float4*)ypartial)[i];
#pragma unroll
    for (int c = 1; c < 8; c++) {
        float4 v = ((const float4*)(ypartial + (size_t)c * 1024 * 1024))[i];
        s.x += v.x; s.y += v.y; s.z += v.z; s.w += v.w;
    }
    bf16x4 o = {(bf16)s.x, (bf16)s.y, (bf16)s.z, (bf16)s.w};
    *(bf16x4*)(y + (size_t)i * 4) = o;
}

// ---------------- MFMA GEMM: 32x32 tile, 4-buf counted-vmcnt pipeline -------
__device__ __forceinline__ void gl16(const bf16* g, bf16* l) {
    __builtin_amdgcn_global_load_lds((const __attribute__((address_space(1))) void*)g,
                                     (__attribute__((address_space(3))) void*)l, 16, 0, 0);
}
__device__ __forceinline__ bf16x8 ldsfrag(const bf16* base, int row, int kb) {
    return *(const bf16x8*)(base + row * 64 + ((kb ^ (row & 7)) << 3));
}

// grid (32, 32): tile M=32, N=32. Wave w -> m-tile (w>>1), n-tile (w&1).
// 4 LDS buffers, issue-ahead 2, vmcnt(4) steady state, 1 raw barrier/K-step,
// s_setprio(1) around the MFMA cluster (waves are phase-split by the pipeline).
template <bool OUT_BF16>
__global__ __launch_bounds__(256) void gemm_kernel(const bf16* __restrict__ A, int lda,
                                                   const bf16* __restrict__ Bt, int ldb,
                                                   const float* __restrict__ bias,
                                                   void* __restrict__ Cv, int ldc, int K) {
    __shared__ bf16 sA[4][2048];   // 32 rows x 64 k per buffer
    __shared__ bf16 sB[4][2048];
    int tid = threadIdx.x;
    int wave = tid >> 6, lane = tid & 63;
    int m0 = blockIdx.x * 32, n0 = blockIdx.y * 32;
    int wr = (wave >> 1) * 16, wc = (wave & 1) * 16;
    int l16 = lane & 15, lhi = lane >> 4;
    int r0 = tid >> 3, kb = tid & 7;     // r0 0..31
    int sk0 = (kb ^ (r0 & 7)) << 3;      // pre-swizzled source col (elems)
    const bf16* A0 = A + (size_t)(m0 + r0) * lda + sk0;
    const bf16* B0 = Bt + (size_t)(n0 + r0) * ldb + sk0;
    int wb = wave * 512;                 // wave-uniform LDS chunk base (elems)

    f32x4 acc = {};

    int nt = K >> 6;
    // prologue: issue tiles 0 and 1
    gl16(A0, &sA[0][wb]);
    gl16(B0, &sB[0][wb]);
    gl16(A0 + 64, &sA[1][wb]);
    gl16(B0 + 64, &sB[1][wb]);
    for (int tI = 0; tI < nt; ++tI) {
        if (tI + 2 < nt) {
            int ko = (tI + 2) << 6;
            gl16(A0 + ko, &sA[(tI + 2) & 3][wb]);
            gl16(B0 + ko, &sB[(tI + 2) & 3][wb]);
        }
        int rem = nt - 1 - tI;
        if (rem >= 2)      asm volatile("s_waitcnt vmcnt(4)" ::: "memory");
        else if (rem == 1) asm volatile("s_waitcnt vmcnt(2)" ::: "memory");
        else               asm volatile("s_waitcnt vmcnt(0)" ::: "memory");
        __builtin_amdgcn_s_barrier();
        __builtin_amdgcn_sched_barrier(0);
        const bf16* a = sA[tI & 3];
        const bf16* bt = sB[tI & 3];
        __builtin_amdgcn_s_setprio(1);
#pragma unroll
        for (int ks = 0; ks < 2; ks++) {
            int kbb = ks * 4 + lhi;
            bf16x8 av = ldsfrag(a, wr + l16, kbb);
            bf16x8 bv = ldsfrag(bt, wc + l16, kbb);
            acc = __builtin_amdgcn_mfma_f32_16x16x32_bf16(av, bv, acc, 0, 0, 0);
        }
        __builtin_amdgcn_s_setprio(0);
    }
#pragma unroll
    for (int r = 0; r < 4; r++) {
        int row = m0 + wr + lhi * 4 + r;
        int col = n0 + wc + l16;
        float v = acc[r] + bias[col];
        if (OUT_BF16)
            ((bf16*)Cv)[(size_t)row * ldc + col] = (bf16)v;
        else
            ((float*)Cv)[(size_t)row * ldc + col] = v;
    }
}

// ---------------- LayerNorm epilogues (modes 0,1) ---------------------------
template <int MODE>
__global__ __launch_bounds__(256) void ln_kernel(const float* __restrict__ C,
                                                 const float* __restrict__ g,
                                                 const float* __restrict__ beta,
                                                 const float* __restrict__ resid,
                                                 void* __restrict__ out) {
    __shared__ float r1[8], r2[8];
    int row = blockIdx.x, t = threadIdx.x;
    float4 v = ((const float4*)(C + (size_t)row * 1024))[t];
    float s = v.x + v.y + v.z + v.w;
    float s2 = v.x * v.x + v.y * v.y + v.z * v.z + v.w * v.w;
    s = wave_sum(s); s2 = wave_sum(s2);
    int wave = t >> 6, lane = t & 63;
    if (lane == 0) { r1[wave] = s; r2[wave] = s2; }
    __syncthreads();
    float S = r1[0] + r1[1] + r1[2] + r1[3];
    float S2 = r2[0] + r2[1] + r2[2] + r2[3];
    float mean = S * (1.f / 1024.f);
    float var = S2 * (1.f / 1024.f) - mean * mean;
    float inv = rsqrtf(var + 1e-5f);
    float4 gv = ((const float4*)g)[t];
    float4 bv = ((const float4*)beta)[t];
    float o[4];
    o[0] = (v.x - mean) * inv * gv.x + bv.x;
    o[1] = (v.y - mean) * inv * gv.y + bv.y;
    o[2] = (v.z - mean) * inv * gv.z + bv.z;
    o[3] = (v.w - mean) * inv * gv.w + bv.w;
    if (MODE == 0) {
        int b = row >> 4;
        const float* x0 = resid + (size_t)b * LCTX * HD + t * 4;
        bf16x4 w = {(bf16)(o[0] + x0[0]), (bf16)(o[1] + x0[1]),
                    (bf16)(o[2] + x0[2]), (bf16)(o[3] + x0[3])};
        *(bf16x4*)((bf16*)out + (size_t)row * 2048 + t * 4) = w;
    } else {
        bf16x4 w = {(bf16)fmaxf(o[0], 0.f), (bf16)fmaxf(o[1], 0.f),
                    (bf16)fmaxf(o[2], 0.f), (bf16)fmaxf(o[3], 0.f)};
        *(bf16x4*)((bf16*)out + (size_t)row * 1024 + t * 4) = w;
    }
}

// ---------------- fused LN(relu) + tile + query_embed + final write ---------
__global__ __launch_bounds__(256) void lnout_kernel(const float* __restrict__ C,
                                                    const float* __restrict__ g,
                                                    const float* __restrict__ beta,
                                                    const float* __restrict__ qe,
                                                    float* __restrict__ out) {
    __shared__ float r1[8], r2[8];
    int row = blockIdx.x, t = threadIdx.x;
    int b = row >> 4, pp = row & 15;
    float4 v = ((const float4*)(C + (size_t)row * 1024))[t];
    float s = v.x + v.y + v.z + v.w;
    float s2 = v.x * v.x + v.y * v.y + v.z * v.z + v.w * v.w;
    s = wave_sum(s); s2 = wave_sum(s2);
    int wave = t >> 6, lane = t & 63;
    if (lane == 0) { r1[wave] = s; r2[wave] = s2; }
    __syncthreads();
    float S = r1[0] + r1[1] + r1[2] + r1[3];
    float S2 = r2[0] + r2[1] + r2[2] + r2[3];
    float mean = S * (1.f / 1024.f);
    float var = S2 * (1.f / 1024.f) - mean * mean;
    float inv = rsqrtf(var + 1e-5f);
    float4 gv = ((const float4*)g)[t];
    float4 bv = ((const float4*)beta)[t];
    float4 ov;
    ov.x = fmaxf((v.x - mean) * inv * gv.x + bv.x, 0.f);
    ov.y = fmaxf((v.y - mean) * inv * gv.y + bv.y, 0.f);
    ov.z = fmaxf((v.z - mean) * inv * gv.z + bv.z, 0.f);
    ov.w = fmaxf((v.w - mean) * inv * gv.w + bv.w, 0.f);
    float* out0 = out;
    float* out1 = out + (size_t)256 * 64 * 1024;
#pragma unroll
    for (int q = 0; q < 16; q++) {
        float4 q0 = ((const float4*)(qe + (size_t)q * 2048))[t];
        float4 q1 = ((const float4*)(qe + (size_t)q * 2048 + 1024))[t];
        size_t orow = ((size_t)(pp * 16 + q) * 64 + b) * 1024;
        ((float4*)(out0 + orow))[t] =
            make_float4(ov.x + q0.x, ov.y + q0.y, ov.z + q0.z, ov.w + q0.w);
        ((float4*)(out1 + orow))[t] =
            make_float4(ov.x + q1.x, ov.y + q1.y, ov.z + q1.z, ov.w + q1.w);
    }
}

extern "C" void kernel_launch(void* const* d_in, const int* in_sizes, int n_in,
                              void* d_out, int out_size, void* d_ws, size_t ws_size,
                              hipStream_t stream) {
    const float* x      = (const float*)d_in[0];
    const float* lq     = (const float*)d_in[1];
    const unsigned char* mask = (const unsigned char*)d_in[2];
    const float* qe     = (const float*)d_in[3];
    const float* W1     = (const float*)d_in[4];
    const float* b1     = (const float*)d_in[5];
    const float* W2     = (const float*)d_in[6];
    const float* W3     = (const float*)d_in[8];
    const float* b3     = (const float*)d_in[9];
    const float* Wc     = (const float*)d_in[10];
    const float* bc     = (const float*)d_in[11];
    const float* gc     = (const float*)d_in[12];
    const float* betac  = (const float*)d_in[13];
    const float* Wf1    = (const float*)d_in[14];
    const float* bf1    = (const float*)d_in[15];
    const float* gf1    = (const float*)d_in[16];
    const float* betaf1 = (const float*)d_in[17];
    const float* Wf2    = (const float*)d_in[18];
    const float* bf2    = (const float*)d_in[19];
    const float* gf2    = (const float*)d_in[20];
    const float* betaf2 = (const float*)d_in[21];

    char* ws = (char*)d_ws;
    const size_t MB = 1 << 20;
    bf16* W3t   = (bf16*)(ws + 0 * MB);
    bf16* Wct   = (bf16*)(ws + 2 * MB);
    bf16* Wf1t  = (bf16*)(ws + 4 * MB);
    bf16* Wf2t  = (bf16*)(ws + 8 * MB);
    bf16* X     = (bf16*)(ws + 10 * MB);
    float* mbuf = (float*)(ws + 14 * MB + 256 * 1024);
    float* attb = (float*)(ws + 14 * MB + 512 * 1024);
    bf16* ybuf  = (bf16*)(ws + 17 * MB);
    bf16* ctxp  = (bf16*)(ws + 19 * MB);
    float* Cbuf = (float*)(ws + 21 * MB);   // 4 MB
    bf16* t1    = (bf16*)(ws + 25 * MB);
    float* ypartial = (float*)(ws + 32 * MB);   // 8 x 4 MB
    // kpart partials alias Cbuf: consumed by mmat before first f32 gemm writes Cbuf
    float* kpartial = Cbuf;

    prep_kernel<<<6400, 256, 0, stream>>>(W3, Wc, Wf1, Wf2, lq, x, W1,
                                          W3t, Wct, Wf1t, Wf2t, X, kpartial);
    mmat_kernel<<<dim3(64, 16), 256, 0, stream>>>(kpartial, b1, W2, mbuf);
    att_kernel<<<dim3(64, 32), 256, 0, stream>>>(x, mbuf, attb);
    ypart_kernel<<<dim3(64, 8), 256, 0, stream>>>(attb, mask, x, ypartial);
    yred_kernel<<<1024, 256, 0, stream>>>(ypartial, ybuf);
    gemm_kernel<true><<<dim3(32, 32), 256, 0, stream>>>(ybuf, 1024, W3t, 1024, b3,
                                                        ctxp, 1024, 1024);
    gemm_kernel<false><<<dim3(32, 32), 256, 0, stream>>>(ctxp, 1024, Wct, 1024, bc,
                                                         Cbuf, 1024, 1024);
    ln_kernel<0><<<1024, 256, 0, stream>>>(Cbuf, gc, betac, x, X);
    gemm_kernel<false><<<dim3(32, 32), 256, 0, stream>>>(X, 2048, Wf1t, 2048, bf1,
                                                         Cbuf, 1024, 2048);
    ln_kernel<1><<<1024, 256, 0, stream>>>(Cbuf, gf1, betaf1, nullptr, t1);
    gemm_kernel<false><<<dim3(32, 32), 256, 0, stream>>>(t1, 1024, Wf2t, 1024, bf2,
                                                         Cbuf, 1024, 1024);
    lnout_kernel<<<1024, 256, 0, stream>>>(Cbuf, gf2, betaf2, qe, (float*)d_out);
}

// Round 16
// 215.982 us; speedup vs baseline: 1.0089x; 1.0089x over previous
//
#include <hip/hip_runtime.h>

typedef __bf16 bf16;
typedef __bf16 bf16x8 __attribute__((ext_vector_type(8)));
typedef __bf16 bf16x4 __attribute__((ext_vector_type(4)));
typedef float f32x4 __attribute__((ext_vector_type(4)));

#define LCTX 512
#define HD 1024

__device__ __forceinline__ float wave_sum(float v) {
    for (int off = 32; off; off >>= 1) v += __shfl_xor(v, off, 64);
    return v;
}
__device__ __forceinline__ float wave_max(float v) {
    for (int off = 32; off; off >>= 1) v = fmaxf(v, __shfl_xor(v, off, 64));
    return v;
}

// ---------------- prep: 4 weight transposes + lqconv + kpart ----------------
// blocks [0,5120): transpose; [5120,6144): lqconv; [6144,6400): kpart
__global__ __launch_bounds__(256) void prep_kernel(const float* __restrict__ W3,
                                                   const float* __restrict__ Wc,
                                                   const float* __restrict__ Wf1,
                                                   const float* __restrict__ Wf2,
                                                   const float* __restrict__ lq,
                                                   const float* __restrict__ x,
                                                   const float* __restrict__ W1,
                                                   bf16* __restrict__ W3t, bf16* __restrict__ Wct,
                                                   bf16* __restrict__ Wf1t, bf16* __restrict__ Wf2t,
                                                   bf16* __restrict__ X,
                                                   float* __restrict__ kpartial) {
    __shared__ __align__(16) char smem[33792];
    int blk = blockIdx.x, t = threadIdx.x;
    if (blk < 5120) {
        float (*tile)[33] = (float(*)[33])smem;
        const float* W; bf16* Wt; int K, N, i;
        if (blk < 1024)      { W = W3;  Wt = W3t;  K = 1024; N = 1024; i = blk; }
        else if (blk < 2048) { W = Wc;  Wt = Wct;  K = 1024; N = 1024; i = blk - 1024; }
        else if (blk < 3072) { W = Wf2; Wt = Wf2t; K = 1024; N = 1024; i = blk - 2048; }
        else                 { W = Wf1; Wt = Wf1t; K = 2048; N = 1024; i = blk - 3072; }
        int k0 = (i >> 5) * 32, n0 = (i & 31) * 32;
        int c = t & 31, r = t >> 5;
#pragma unroll
        for (int j = 0; j < 4; j++)
            tile[r + j * 8][c] = W[(size_t)(k0 + r + j * 8) * N + n0 + c];
        __syncthreads();
#pragma unroll
        for (int j = 0; j < 4; j++)
            Wt[(size_t)(n0 + r + j * 8) * K + k0 + c] = (bf16)tile[c][r + j * 8];
    } else if (blk < 6144) {
        int i = (blk - 5120) * 256 + t;    // over 262144 float4s
        float4 v = ((const float4*)lq)[i];
        int row = i >> 8, h4 = i & 255;
        bf16x4 o = {(bf16)v.x, (bf16)v.y, (bf16)v.z, (bf16)v.w};
        *(bf16x4*)(X + (size_t)row * 2048 + 1024 + h4 * 4) = o;
    } else {
        // kpart: K-split f32 GEMM  M=64(batch) N=1024 K=1024, token-0 rows
        float (*xs)[68] = (float(*)[68])smem;
        float (*wsm)[64] = (float(*)[64])(smem + 17408);
        int kv = blk - 6144;                    // 0..255
        int n0 = (kv & 15) * 64, k0 = (kv >> 4) * 64;
#pragma unroll
        for (int i = 0; i < 4; i++) {
            int f = t + i * 256;
            int b = f >> 4, c = f & 15;
            *(float4*)&xs[b][c * 4] =
                *(const float4*)(x + (size_t)b * LCTX * HD + k0 + c * 4);
        }
#pragma unroll
        for (int i = 0; i < 4; i++) {
            int f = t + i * 256;
            int r = f >> 4, c = f & 15;
            *(float4*)&wsm[r][c * 4] =
                *(const float4*)(W1 + (size_t)(k0 + r) * 1024 + n0 + c * 4);
        }
        __syncthreads();
        int tb = t >> 4, tc = t & 15;
        int b0 = tb * 4;
        float acc[4][4] = {};
        for (int kk = 0; kk < 64; kk += 4) {
            float4 w0 = *(const float4*)&wsm[kk + 0][tc * 4];
            float4 w1 = *(const float4*)&wsm[kk + 1][tc * 4];
            float4 w2 = *(const float4*)&wsm[kk + 2][tc * 4];
            float4 w3 = *(const float4*)&wsm[kk + 3][tc * 4];
            float4 xv[4];
#pragma unroll
            for (int bi = 0; bi < 4; bi++) xv[bi] = *(const float4*)&xs[b0 + bi][kk];
#pragma unroll
            for (int bi = 0; bi < 4; bi++) {
                acc[bi][0] += xv[bi].x * w0.x + xv[bi].y * w1.x + xv[bi].z * w2.x + xv[bi].w * w3.x;
                acc[bi][1] += xv[bi].x * w0.y + xv[bi].y * w1.y + xv[bi].z * w2.y + xv[bi].w * w3.y;
                acc[bi][2] += xv[bi].x * w0.z + xv[bi].y * w1.z + xv[bi].z * w2.z + xv[bi].w * w3.z;
                acc[bi][3] += xv[bi].x * w0.w + xv[bi].y * w1.w + xv[bi].z * w2.w + xv[bi].w * w3.w;
            }
        }
        float* pout = kpartial + ((size_t)(kv >> 4) * 64 + b0) * 1024 + n0 + tc * 4;
#pragma unroll
        for (int bi = 0; bi < 4; bi++)
            *(float4*)(pout + (size_t)bi * 1024) =
                make_float4(acc[bi][0], acc[bi][1], acc[bi][2], acc[bi][3]);
    }
}

// ---------------- mmat (+inline kreduce): m[b,i] = W2[i,:] . k[b,:] ---------
__global__ __launch_bounds__(256) void mmat_kernel(const float* __restrict__ partial,
                                                   const float* __restrict__ b1,
                                                   const float* __restrict__ W2,
                                                   float* __restrict__ mout) {
    __shared__ float ks[1024];
    int b = blockIdx.x, i0 = blockIdx.y * 64, t = threadIdx.x;
    {
        float4 acc = ((const float4*)b1)[t];
#pragma unroll
        for (int kt = 0; kt < 16; kt++) {
            float4 v = ((const float4*)(partial + ((size_t)kt * 64 + b) * 1024))[t];
            acc.x += v.x; acc.y += v.y; acc.z += v.z; acc.w += v.w;
        }
        *(float4*)&ks[t * 4] = acc;
    }
    __syncthreads();
    int wave = t >> 6, lane = t & 63;
    for (int rr = 0; rr < 16; rr++) {
        int i = i0 + wave * 16 + rr;
        const float* wrow = W2 + (size_t)i * 1024;
        float s = 0.f;
#pragma unroll
        for (int j = 0; j < 4; j++) {
            float4 wv = ((const float4*)wrow)[lane + j * 64];
            const float4 kv = *(const float4*)&ks[(lane + j * 64) * 4];
            s += wv.x * kv.x + wv.y * kv.y + wv.z * kv.z + wv.w * kv.w;
        }
        s = wave_sum(s);
        if (lane == 0) mout[(size_t)b * 1024 + i] = s;
    }
}

// ---------------- att[b,l] = x[b,l,:] . m[b,:]  grid (64,32) ----------------
__global__ __launch_bounds__(256) void att_kernel(const float* __restrict__ x,
                                                  const float* __restrict__ m,
                                                  float* __restrict__ att) {
    __shared__ float ms[1024];
    int b = blockIdx.x, l0 = blockIdx.y * 16, t = threadIdx.x;
    *(float4*)&ms[t * 4] = ((const float4*)(m + (size_t)b * 1024))[t];
    __syncthreads();
    int wave = t >> 6, lane = t & 63;
    for (int rr = 0; rr < 4; rr++) {
        int l = l0 + wave * 4 + rr;
        const float* xr = x + ((size_t)b * LCTX + l) * HD;
        float s = 0.f;
#pragma unroll
        for (int j = 0; j < 4; j++) {
            float4 xv = ((const float4*)xr)[lane + j * 64];
            const float4 mv = *(const float4*)&ms[(lane + j * 64) * 4];
            s += xv.x * mv.x + xv.y * mv.y + xv.z * mv.z + xv.w * mv.w;
        }
        s = wave_sum(s);
        if (lane == 0) att[(size_t)b * LCTX + l] = s;
    }
}

// ---------------- ypart: softmax + partial y; ps stored TRANSPOSED ----------
// grid (64, 8): 512 blocks, 2/CU. ps_T[64][16] -> 4x ds_read_b128 per l-iter.
__global__ __launch_bounds__(256) void ypart_kernel(const float* __restrict__ att,
                                                    const unsigned char* __restrict__ mask,
                                                    const float* __restrict__ x,
                                                    float* __restrict__ ypartial) {
    __shared__ float psT[64][16];      // [l_local][pp]
    __shared__ float att_s[512];
    __shared__ int sstr;
    int b = blockIdx.x, lqi = blockIdx.y, t = threadIdx.x;
    int l0 = lqi * 64;
    int wave = t >> 6, lane = t & 63;
    if (t == 0) sstr = 4;
    if (t < 128) ((float4*)att_s)[t] = ((const float4*)(att + (size_t)b * LCTX))[t];
    __syncthreads();
    if (t < 128 && ((const unsigned int*)mask)[t] > 1u) sstr = 1;
    __syncthreads();
    int stride = sstr;
#pragma unroll
    for (int q = 0; q < 4; q++) {
        int pp = wave * 4 + q;
        size_t mbase = ((size_t)(b * 16 + pp)) * LCTX;
        float av[8];
#pragma unroll
        for (int j = 0; j < 8; j++) {
            int l = lane + j * 64;
            bool mk = mask[(mbase + l) * (size_t)stride] != 0;
            av[j] = mk ? -1e30f : att_s[l];
        }
        float mx = av[0];
#pragma unroll
        for (int j = 1; j < 8; j++) mx = fmaxf(mx, av[j]);
        mx = wave_max(mx);
        float s = 0.f;
#pragma unroll
        for (int j = 0; j < 8; j++) {
            av[j] = (av[j] <= -1e29f) ? 0.f : expf(av[j] - mx);
            s += av[j];
        }
        s = wave_sum(s);
        float sel = av[0];
#pragma unroll
        for (int j = 1; j < 8; j++) if (lqi == j) sel = av[j];
        psT[lane][pp] = sel * (1.f / s);
    }
    __syncthreads();
    float4 acc[16];
#pragma unroll
    for (int q = 0; q < 16; q++) acc[q] = make_float4(0.f, 0.f, 0.f, 0.f);
    const float4* xb = (const float4*)(x + ((size_t)b * LCTX + l0) * HD) + t;
    float4 xv = xb[0];
    for (int l = 0; l < 64; l++) {
        float4 cur = xv;
        if (l < 63) xv = xb[(size_t)(l + 1) * 256];   // prefetch next row
        f32x4 pv0 = *(const f32x4*)&psT[l][0];
        f32x4 pv1 = *(const f32x4*)&psT[l][4];
        f32x4 pv2 = *(const f32x4*)&psT[l][8];
        f32x4 pv3 = *(const f32x4*)&psT[l][12];
#pragma unroll
        for (int g = 0; g < 4; g++) {
            f32x4 pv = g == 0 ? pv0 : (g == 1 ? pv1 : (g == 2 ? pv2 : pv3));
#pragma unroll
            for (int j = 0; j < 4; j++) {
                float p = pv[j];
                int q = g * 4 + j;
                acc[q].x += p * cur.x; acc[q].y += p * cur.y;
                acc[q].z += p * cur.z; acc[q].w += p * cur.w;
            }
        }
    }
    float* yp = ypartial + ((size_t)lqi * 1024 + b * 16) * 1024 + t * 4;
#pragma unroll
    for (int q = 0; q < 16; q++)
        *(float4*)(yp + (size_t)q * 1024) = acc[q];
}

// ---------------- yred: y = bf16( sum of 8 partials ) -----------------------
__global__ __launch_bounds__(256) void yred_kernel(const float* __restrict__ ypartial,
                                                   bf16* __restrict__ y) {
    int i = blockIdx.x * 256 + threadIdx.x;   // over 262144 float4s of y
    float4 s = ((const float4*)ypartial)[i];
#pragma unroll
    for (int c = 1; c < 8; c++) {
        float4 v = ((const float4*)(ypartial + (size_t)c * 1024 * 1024))[i];
        s.x += v.x; s.y += v.y; s.z += v.z; s.w += v.w;
    }
    bf16x4 o = {(bf16)s.x, (bf16)s.y, (bf16)s.z, (bf16)s.w};
    *(bf16x4*)(y + (size_t)i * 4) = o;
}

// ---------------- MFMA GEMM: 32x32 tile, 4-buf counted-vmcnt pipeline -------
__device__ __forceinline__ void gl16(const bf16* g, bf16* l) {
    __builtin_amdgcn_global_load_lds((const __attribute__((address_space(1))) void*)g,
                                     (__attribute__((address_space(3))) void*)l, 16, 0, 0);
}
__device__ __forceinline__ bf16x8 ldsfrag(const bf16* base, int row, int kb) {
    return *(const bf16x8*)(base + row * 64 + ((kb ^ (row & 7)) << 3));
}

// grid (32, 32): tile M=32, N=32. Wave w -> m-tile (w>>1), n-tile (w&1).
// 4 LDS buffers, issue-ahead 2, vmcnt(4) steady state, 1 raw barrier/K-step.
template <bool OUT_BF16>
__global__ __launch_bounds__(256) void gemm_kernel(const bf16* __restrict__ A, int lda,
                                                   const bf16* __restrict__ Bt, int ldb,
                                                   const float* __restrict__ bias,
                                                   void* __restrict__ Cv, int ldc, int K) {
    __shared__ bf16 sA[4][2048];   // 32 rows x 64 k per buffer
    __shared__ bf16 sB[4][2048];
    int tid = threadIdx.x;
    int wave = tid >> 6, lane = tid & 63;
    int m0 = blockIdx.x * 32, n0 = blockIdx.y * 32;
    int wr = (wave >> 1) * 16, wc = (wave & 1) * 16;
    int l16 = lane & 15, lhi = lane >> 4;
    int r0 = tid >> 3, kb = tid & 7;     // r0 0..31
    int sk0 = (kb ^ (r0 & 7)) << 3;      // pre-swizzled source col (elems)
    const bf16* A0 = A + (size_t)(m0 + r0) * lda + sk0;
    const bf16* B0 = Bt + (size_t)(n0 + r0) * ldb + sk0;
    int wb = wave * 512;                 // wave-uniform LDS chunk base (elems)

    f32x4 acc = {};

    int nt = K >> 6;
    // prologue: issue tiles 0 and 1
    gl16(A0, &sA[0][wb]);
    gl16(B0, &sB[0][wb]);
    gl16(A0 + 64, &sA[1][wb]);
    gl16(B0 + 64, &sB[1][wb]);
    for (int tI = 0; tI < nt; ++tI) {
        if (tI + 2 < nt) {
            int ko = (tI + 2) << 6;
            gl16(A0 + ko, &sA[(tI + 2) & 3][wb]);
            gl16(B0 + ko, &sB[(tI + 2) & 3][wb]);
        }
        int rem = nt - 1 - tI;
        if (rem >= 2)      asm volatile("s_waitcnt vmcnt(4)" ::: "memory");
        else if (rem == 1) asm volatile("s_waitcnt vmcnt(2)" ::: "memory");
        else               asm volatile("s_waitcnt vmcnt(0)" ::: "memory");
        __builtin_amdgcn_s_barrier();
        __builtin_amdgcn_sched_barrier(0);
        const bf16* a = sA[tI & 3];
        const bf16* bt = sB[tI & 3];
#pragma unroll
        for (int ks = 0; ks < 2; ks++) {
            int kbb = ks * 4 + lhi;
            bf16x8 av = ldsfrag(a, wr + l16, kbb);
            bf16x8 bv = ldsfrag(bt, wc + l16, kbb);
            acc = __builtin_amdgcn_mfma_f32_16x16x32_bf16(av, bv, acc, 0, 0, 0);
        }
    }
#pragma unroll
    for (int r = 0; r < 4; r++) {
        int row = m0 + wr + lhi * 4 + r;
        int col = n0 + wc + l16;
        float v = acc[r] + bias[col];
        if (OUT_BF16)
            ((bf16*)Cv)[(size_t)row * ldc + col] = (bf16)v;
        else
            ((float*)Cv)[(size_t)row * ldc + col] = v;
    }
}

// ---------------- LayerNorm epilogues (modes 0,1) ---------------------------
template <int MODE>
__global__ __launch_bounds__(256) void ln_kernel(const float* __restrict__ C,
                                                 const float* __restrict__ g,
                                                 const float* __restrict__ beta,
                                                 const float* __restrict__ resid,
                                                 void* __restrict__ out) {
    __shared__ float r1[8], r2[8];
    int row = blockIdx.x, t = threadIdx.x;
    float4 v = ((const float4*)(C + (size_t)row * 1024))[t];
    float s = v.x + v.y + v.z + v.w;
    float s2 = v.x * v.x + v.y * v.y + v.z * v.z + v.w * v.w;
    s = wave_sum(s); s2 = wave_sum(s2);
    int wave = t >> 6, lane = t & 63;
    if (lane == 0) { r1[wave] = s; r2[wave] = s2; }
    __syncthreads();
    float S = r1[0] + r1[1] + r1[2] + r1[3];
    float S2 = r2[0] + r2[1] + r2[2] + r2[3];
    float mean = S * (1.f / 1024.f);
    float var = S2 * (1.f / 1024.f) - mean * mean;
    float inv = rsqrtf(var + 1e-5f);
    float4 gv = ((const float4*)g)[t];
    float4 bv = ((const float4*)beta)[t];
    float o[4];
    o[0] = (v.x - mean) * inv * gv.x + bv.x;
    o[1] = (v.y - mean) * inv * gv.y + bv.y;
    o[2] = (v.z - mean) * inv * gv.z + bv.z;
    o[3] = (v.w - mean) * inv * gv.w + bv.w;
    if (MODE == 0) {
        int b = row >> 4;
        const float* x0 = resid + (size_t)b * LCTX * HD + t * 4;
        bf16x4 w = {(bf16)(o[0] + x0[0]), (bf16)(o[1] + x0[1]),
                    (bf16)(o[2] + x0[2]), (bf16)(o[3] + x0[3])};
        *(bf16x4*)((bf16*)out + (size_t)row * 2048 + t * 4) = w;
    } else {
        bf16x4 w = {(bf16)fmaxf(o[0], 0.f), (bf16)fmaxf(o[1], 0.f),
                    (bf16)fmaxf(o[2], 0.f), (bf16)fmaxf(o[3], 0.f)};
        *(bf16x4*)((bf16*)out + (size_t)row * 1024 + t * 4) = w;
    }
}

// ---------------- fused LN(relu) + tile + query_embed + final write ---------
__global__ __launch_bounds__(256) void lnout_kernel(const float* __restrict__ C,
                                                    const float* __restrict__ g,
                                                    const float* __restrict__ beta,
                                                    const float* __restrict__ qe,
                                                    float* __restrict__ out) {
    __shared__ float r1[8], r2[8];
    int row = blockIdx.x, t = threadIdx.x;
    int b = row >> 4, pp = row & 15;
    float4 v = ((const float4*)(C + (size_t)row * 1024))[t];
    float s = v.x + v.y + v.z + v.w;
    float s2 = v.x * v.x + v.y * v.y + v.z * v.z + v.w * v.w;
    s = wave_sum(s); s2 = wave_sum(s2);
    int wave = t >> 6, lane = t & 63;
    if (lane == 0) { r1[wave] = s; r2[wave] = s2; }
    __syncthreads();
    float S = r1[0] + r1[1] + r1[2] + r1[3];
    float S2 = r2[0] + r2[1] + r2[2] + r2[3];
    float mean = S * (1.f / 1024.f);
    float var = S2 * (1.f / 1024.f) - mean * mean;
    float inv = rsqrtf(var + 1e-5f);
    float4 gv = ((const float4*)g)[t];
    float4 bv = ((const float4*)beta)[t];
    float4 ov;
    ov.x = fmaxf((v.x - mean) * inv * gv.x + bv.x, 0.f);
    ov.y = fmaxf((v.y - mean) * inv * gv.y + bv.y, 0.f);
    ov.z = fmaxf((v.z - mean) * inv * gv.z + bv.z, 0.f);
    ov.w = fmaxf((v.w - mean) * inv * gv.w + bv.w, 0.f);
    float* out0 = out;
    float* out1 = out + (size_t)256 * 64 * 1024;
#pragma unroll
    for (int q = 0; q < 16; q++) {
        float4 q0 = ((const float4*)(qe + (size_t)q * 2048))[t];
        float4 q1 = ((const float4*)(qe + (size_t)q * 2048 + 1024))[t];
        size_t orow = ((size_t)(pp * 16 + q) * 64 + b) * 1024;
        ((float4*)(out0 + orow))[t] =
            make_float4(ov.x + q0.x, ov.y + q0.y, ov.z + q0.z, ov.w + q0.w);
        ((float4*)(out1 + orow))[t] =
            make_float4(ov.x + q1.x, ov.y + q1.y, ov.z + q1.z, ov.w + q1.w);
    }
}

extern "C" void kernel_launch(void* const* d_in, const int* in_sizes, int n_in,
                              void* d_out, int out_size, void* d_ws, size_t ws_size,
                              hipStream_t stream) {
    const float* x      = (const float*)d_in[0];
    const float* lq     = (const float*)d_in[1];
    const unsigned char* mask = (const unsigned char*)d_in[2];
    const float* qe     = (const float*)d_in[3];
    const float* W1     = (const float*)d_in[4];
    const float* b1     = (const float*)d_in[5];
    const float* W2     = (const float*)d_in[6];
    const float* W3     = (const float*)d_in[8];
    const float* b3     = (const float*)d_in[9];
    const float* Wc     = (const float*)d_in[10];
    const float* bc     = (const float*)d_in[11];
    const float* gc     = (const float*)d_in[12];
    const float* betac  = (const float*)d_in[13];
    const float* Wf1    = (const float*)d_in[14];
    const float* bf1    = (const float*)d_in[15];
    const float* gf1    = (const float*)d_in[16];
    const float* betaf1 = (const float*)d_in[17];
    const float* Wf2    = (const float*)d_in[18];
    const float* bf2    = (const float*)d_in[19];
    const float* gf2    = (const float*)d_in[20];
    const float* betaf2 = (const float*)d_in[21];

    char* ws = (char*)d_ws;
    const size_t MB = 1 << 20;
    bf16* W3t   = (bf16*)(ws + 0 * MB);
    bf16* Wct   = (bf16*)(ws + 2 * MB);
    bf16* Wf1t  = (bf16*)(ws + 4 * MB);
    bf16* Wf2t  = (bf16*)(ws + 8 * MB);
    bf16* X     = (bf16*)(ws + 10 * MB);
    float* mbuf = (float*)(ws + 14 * MB + 256 * 1024);
    float* attb = (float*)(ws + 14 * MB + 512 * 1024);
    bf16* ybuf  = (bf16*)(ws + 17 * MB);
    bf16* ctxp  = (bf16*)(ws + 19 * MB);
    float* Cbuf = (float*)(ws + 21 * MB);   // 4 MB
    bf16* t1    = (bf16*)(ws + 25 * MB);
    float* ypartial = (float*)(ws + 32 * MB);   // 8 x 4 MB
    // kpart partials alias Cbuf: consumed by mmat before first f32 gemm writes Cbuf
    float* kpartial = Cbuf;

    prep_kernel<<<6400, 256, 0, stream>>>(W3, Wc, Wf1, Wf2, lq, x, W1,
                                          W3t, Wct, Wf1t, Wf2t, X, kpartial);
    mmat_kernel<<<dim3(64, 16), 256, 0, stream>>>(kpartial, b1, W2, mbuf);
    att_kernel<<<dim3(64, 32), 256, 0, stream>>>(x, mbuf, attb);
    ypart_kernel<<<dim3(64, 8), 256, 0, stream>>>(attb, mask, x, ypartial);
    yred_kernel<<<1024, 256, 0, stream>>>(ypartial, ybuf);
    gemm_kernel<true><<<dim3(32, 32), 256, 0, stream>>>(ybuf, 1024, W3t, 1024, b3,
                                                        ctxp, 1024, 1024);
    gemm_kernel<false><<<dim3(32, 32), 256, 0, stream>>>(ctxp, 1024, Wct, 1024, bc,
                                                         Cbuf, 1024, 1024);
    ln_kernel<0><<<1024, 256, 0, stream>>>(Cbuf, gc, betac, x, X);
    gemm_kernel<false><<<dim3(32, 32), 256, 0, stream>>>(X, 2048, Wf1t, 2048, bf1,
                                                         Cbuf, 1024, 2048);
    ln_kernel<1><<<1024, 256, 0, stream>>>(Cbuf, gf1, betaf1, nullptr, t1);
    gemm_kernel<false><<<dim3(32, 32), 256, 0, stream>>>(t1, 1024, Wf2t, 1024, bf2,
                                                         Cbuf, 1024, 1024);
    lnout_kernel<<<1024, 256, 0, stream>>>(Cbuf, gf2, betaf2, qe, (float*)d_out);
}